// Round 1
// baseline (939.495 us; speedup 1.0000x reference)
//
#include <hip/hip_runtime.h>
#include <math.h>

#define Dd 128
#define Tt 1024
#define Kk 2048
#define Nn 65536
#define DT 131072  // Dd*Tt

typedef __attribute__((ext_vector_type(8))) short short8;
typedef __attribute__((ext_vector_type(4))) float float4v;

// ws layout (bytes):
//   cbh     @ 0        : ushort[262144] = 524288   (bf16 hi plane of codebook, [k][d])
//   e2f     @ 524288   : float[2048]    = 8192     (np-replica fp32 ||e||^2)
//   Arow    @ 532480   : float[65536]   = 262144   (np-replica fp32 ||x||^2)
//   idxbuf  @ 794624   : int[65536]     = 262144
//   counts  @ 1056768  : int[2048]      = 8192
//   part    @ 1064960  : double[512]    = 4096
//   cand_g  @ 1069056  : ushort[65536*16] = 2097152
//   candcnt @ 3166208  : int[65536]     = 262144
// total 3428352 B (~3.43 MB)

__device__ __forceinline__ void gload16(const void* g, void* l) {
  // 16B global->LDS direct copy; LDS dest = wave-uniform base + lane*16.
  __builtin_amdgcn_global_load_lds(
      (const __attribute__((address_space(1))) unsigned int*)g,
      (__attribute__((address_space(3))) unsigned int*)l, 16, 0, 0);
}

// Fused setup: bf16-hi split of codebook + zero histogram (blocks 0..1023),
// np-replica fp32 ||e||^2 (blocks 1024..1031), np-replica fp32 ||x||^2
// (blocks 1032..1287). numpy pairwise order for n=128: 8 accumulators,
// sequential i, combine ((r0+r1)+(r2+r3))+((r4+r5)+(r6+r7)); __f*_rn blocks
// FMA contraction so each square rounds like numpy's flat*flat.
__global__ __launch_bounds__(256)
void setup_kernel(const float* __restrict__ cb, const float* __restrict__ z,
                  ushort* __restrict__ cbh, float* __restrict__ e2f,
                  float* __restrict__ Arow, int* __restrict__ counts) {
  const int bid = blockIdx.x, tid = threadIdx.x;
  if (bid < 1024) {
    const int g = bid * 256 + tid;                // 262144 codebook elems
    const float v = cb[g];
    const unsigned u = __float_as_uint(v);
    const unsigned hb = (u + 0x7FFFu + ((u >> 16) & 1u)) & 0xFFFF0000u;  // RNE bf16
    cbh[g] = (ushort)(hb >> 16);
    if (g < Kk) counts[g] = 0;
  } else if (bid < 1032) {
    const int k = (bid - 1024) * 256 + tid;       // 2048 codes
    const float* p = cb + (size_t)k * Dd;
    float r[8];
    #pragma unroll
    for (int j = 0; j < 8; ++j) r[j] = __fmul_rn(p[j], p[j]);
    for (int i = 1; i < 16; ++i) {
      #pragma unroll
      for (int j = 0; j < 8; ++j) {
        const float v = p[8 * i + j];
        r[j] = __fadd_rn(r[j], __fmul_rn(v, v));
      }
    }
    e2f[k] = __fadd_rn(__fadd_rn(__fadd_rn(r[0], r[1]), __fadd_rn(r[2], r[3])),
                       __fadd_rn(__fadd_rn(r[4], r[5]), __fadd_rn(r[6], r[7])));
  } else {
    const int g = (bid - 1032) * 256 + tid;       // 65536 rows
    const int b = g >> 10, t = g & 1023;
    const float* p = z + (size_t)b * DT + t;      // x_d = p[d*Tt]
    float r[8];
    #pragma unroll
    for (int j = 0; j < 8; ++j) {
      const float v = p[j * Tt];
      r[j] = __fmul_rn(v, v);
    }
    for (int i = 1; i < 16; ++i) {
      #pragma unroll
      for (int j = 0; j < 8; ++j) {
        const float v = p[(8 * i + j) * Tt];
        r[j] = __fadd_rn(r[j], __fmul_rn(v, v));
      }
    }
    Arow[g] = __fadd_rn(__fadd_rn(__fadd_rn(r[0], r[1]), __fadd_rn(r[2], r[3])),
                        __fadd_rn(__fadd_rn(r[4], r[5]), __fadd_rn(r[6], r[7])));
  }
}

// Phase 1 (rewritten): single-sweep hi-plane bf16 MFMA scoring.
// 128 rows/block (512 blocks), 4 waves = 2 row-halves x 2 col-halves.
// A (z rows) lives in registers for the whole K loop; B (codebook chunk,
// 64 codes x 128d) is staged double-buffered via global_load_lds with
// pre-swizzled source addresses (LDS dest stays linear). Online gating:
// per-lane running row-min; append candidates with s < runmin + margB
// (block-max margin) into capacity-24 LDS lists (superset of the exact
// criterion at all times). Iterations 0..3 are a no-append warm-up over
// chunks 0..3 to seed the gate; cross-lane min-shares at it=3/11/19/27.
// Post-loop: exact global row-min reduce, then filter lists with the
// exact per-row threshold rowmin + marg_row (identical semantics to the
// old sweep-B). Overflow (>24) -> candcnt=17 -> exact fallback.
__global__ __launch_bounds__(256, 2)
void score_kernel(const float* __restrict__ z, const ushort* __restrict__ cbh,
                  const float* __restrict__ e2f, const float* __restrict__ Arow,
                  ushort* __restrict__ cand_g, int* __restrict__ candcnt) {
  __shared__ __attribute__((aligned(16))) ushort eh[16384]; // 32KB: zh (prologue) -> 2x16KB chunk dbuf
  __shared__ float e2s[2048];       // 8KB
  __shared__ float margL[128];
  __shared__ float sredA[256];      // [row][wc] wave minima
  __shared__ float thrF[128];       // final exact thresholds
  __shared__ int cntL[128];
  __shared__ float candS[128 * 24]; // 12KB candidate scores
  __shared__ ushort candI[128 * 24];// 6KB candidate indices

  const int tid = threadIdx.x;
  const int n0 = blockIdx.x * 128;               // 512 blocks
  const int b = n0 >> 10, t0 = n0 & 1023;
  const float* zb = z + (size_t)b * DT + t0;
  const int lane = tid & 63, wv = tid >> 6;
  const int col = lane & 15, quad = lane >> 4;
  const int wr = wv >> 1, wc = wv & 1;

  // ---- prologue: stage z hi plane (128 rows x 128 d, 16B-granule swizzled) ----
  {
    const int i = tid & 127;          // row in block
    const int half = tid >> 7;        // 0/1
    #pragma unroll
    for (int g8 = 0; g8 < 8; ++g8) {
      const int gran = half * 8 + g8;
      short8 w;
      #pragma unroll
      for (int j = 0; j < 8; ++j) {
        const int d = gran * 8 + j;
        const float v = zb[d * Tt + i];            // coalesced over i
        const unsigned u = __float_as_uint(v);
        const unsigned hb = (u + 0x7FFFu + ((u >> 16) & 1u)) & 0xFFFF0000u;
        w[j] = (short)(hb >> 16);
      }
      *(short8*)&eh[i * 128 + ((gran ^ (i & 15)) << 3)] = w;
    }
  }
  #pragma unroll
  for (int j = 0; j < 8; ++j) e2s[tid + 256 * j] = e2f[tid + 256 * j];
  if (tid < 128) {
    margL[tid] = 8.7e-5f * sqrtf(Arow[n0 + tid]) + 1.0e-4f;
    cntL[tid] = 0;
  }
  __syncthreads();

  // ---- A fragments into registers (64 rows per wave, K=128) ----
  short8 afr[4][4];
  #pragma unroll
  for (int rt = 0; rt < 4; ++rt)
    #pragma unroll
    for (int ks = 0; ks < 4; ++ks) {
      const int rw = wr * 64 + rt * 16 + col;     // rw&15 == col
      afr[rt][ks] = *(const short8*)&eh[rw * 128 + (((ks * 4 + quad) ^ col) << 3)];
    }
  // block-max margin (gate only; final filter uses exact per-row margin)
  float margB;
  {
    float m = fmaxf(margL[lane], margL[64 + lane]);
    #pragma unroll
    for (int o = 1; o < 64; o <<= 1) m = fmaxf(m, __shfl_xor(m, o, 64));
    margB = m;
  }
  float runmin[16], thr[16];
  #pragma unroll
  for (int sl = 0; sl < 16; ++sl) { runmin[sl] = 1e30f; thr[sl] = 1e30f; }
  __syncthreads();  // all A-frag reads done before chunk staging overwrites zh

  // stage chunk 0 into buf 0 (source pre-swizzled, LDS linear)
  #pragma unroll
  for (int j = 0; j < 4; ++j) {
    const int gidx = j * 256 + wv * 64 + lane;
    const int c = gidx >> 4;
    const int kb = (gidx & 15) ^ (c & 15);
    gload16(cbh + (((size_t)c) << 7) + (kb << 3), &eh[(j * 256 + wv * 64) * 8]);
  }

  const float4v vzero = {0.f, 0.f, 0.f, 0.f};
  // 36 iterations: it 0..3 = warm-up over chunks 0..3 (no appends),
  // it 4..35 = chunks 0..31 with appends.
  for (int it = 0; it < 36; ++it) {
    __syncthreads();   // drains in-flight gload_lds (chunk for this iter) + buffer protect
    if (it < 35) {
      const int nc = (it + 1 < 4) ? (it + 1) : (it + 1 - 4);
      const int nb = ((it + 1) & 1) * 8192;
      #pragma unroll
      for (int j = 0; j < 4; ++j) {
        const int gidx = j * 256 + wv * 64 + lane;
        const int c = gidx >> 4;
        const int kb = (gidx & 15) ^ (c & 15);
        gload16(cbh + (((size_t)(nc * 64 + c)) << 7) + (kb << 3),
                &eh[nb + (j * 256 + wv * 64) * 8]);
      }
    }
    const int cc = (it < 4) ? it : it - 4;
    const ushort* eb = eh + (it & 1) * 8192;
    float4v acc[4][2];
    #pragma unroll
    for (int rt = 0; rt < 4; ++rt) { acc[rt][0] = vzero; acc[rt][1] = vzero; }
    #pragma unroll
    for (int ks = 0; ks < 4; ++ks) {
      const int ph = ((ks * 4 + quad) ^ col) << 3;
      const short8 b0 = *(const short8*)&eb[(wc * 32 + col) * 128 + ph];
      const short8 b1 = *(const short8*)&eb[(wc * 32 + 16 + col) * 128 + ph];
      #pragma unroll
      for (int rt = 0; rt < 4; ++rt) {
        acc[rt][0] = __builtin_amdgcn_mfma_f32_16x16x32_bf16(afr[rt][ks], b0, acc[rt][0], 0, 0, 0);
        acc[rt][1] = __builtin_amdgcn_mfma_f32_16x16x32_bf16(afr[rt][ks], b1, acc[rt][1], 0, 0, 0);
      }
    }
    const int cbase = cc * 64 + wc * 32 + col;
    const float e20 = e2s[cbase];
    const float e21 = e2s[cbase + 16];
    const bool doapp = (it >= 4);
    #pragma unroll
    for (int rt = 0; rt < 4; ++rt)
      #pragma unroll
      for (int r = 0; r < 4; ++r) {
        const int sl = rt * 4 + r;
        const float s0 = fmaf(-2.0f, acc[rt][0][r], e20);
        const float s1 = fmaf(-2.0f, acc[rt][1][r], e21);
        if (doapp) {
          if (s0 < thr[sl]) {
            const int rw = wr * 64 + rt * 16 + quad * 4 + r;
            const int pos = atomicAdd(&cntL[rw], 1);
            if (pos < 24) { candS[rw * 24 + pos] = s0; candI[rw * 24 + pos] = (ushort)cbase; }
          }
          if (s1 < thr[sl]) {
            const int rw = wr * 64 + rt * 16 + quad * 4 + r;
            const int pos = atomicAdd(&cntL[rw], 1);
            if (pos < 24) { candS[rw * 24 + pos] = s1; candI[rw * 24 + pos] = (ushort)(cbase + 16); }
          }
        }
        runmin[sl] = fminf(runmin[sl], fminf(s0, s1));
      }
    if (it == 3 || it == 11 || it == 19 || it == 27) {
      #pragma unroll
      for (int sl = 0; sl < 16; ++sl) {
        float v = runmin[sl];
        v = fminf(v, __shfl_xor(v, 1, 64));
        v = fminf(v, __shfl_xor(v, 2, 64));
        v = fminf(v, __shfl_xor(v, 4, 64));
        v = fminf(v, __shfl_xor(v, 8, 64));
        runmin[sl] = v;
      }
    }
    #pragma unroll
    for (int sl = 0; sl < 16; ++sl) thr[sl] = runmin[sl] + margB;
  }

  // ---- exact global row-min + exact-threshold filter ----
  #pragma unroll
  for (int sl = 0; sl < 16; ++sl) {
    float v = runmin[sl];
    v = fminf(v, __shfl_xor(v, 1, 64));
    v = fminf(v, __shfl_xor(v, 2, 64));
    v = fminf(v, __shfl_xor(v, 4, 64));
    v = fminf(v, __shfl_xor(v, 8, 64));
    if (col == 0) {
      const int rw = wr * 64 + (sl >> 2) * 16 + quad * 4 + (sl & 3);
      sredA[rw * 2 + wc] = v;
    }
  }
  __syncthreads();
  if (tid < 128) thrF[tid] = fminf(sredA[tid * 2], sredA[tid * 2 + 1]) + margL[tid];
  __syncthreads();
  if (tid < 128) {
    const int n = n0 + tid;
    const int c = cntL[tid];
    const int cl = c < 24 ? c : 24;
    int m = 0;
    for (int j = 0; j < cl; ++j) {
      if (candS[tid * 24 + j] < thrF[tid]) {
        if (m < 16) cand_g[(size_t)n * 16 + m] = candI[tid * 24 + j];
        ++m;
      }
    }
    candcnt[n] = (c > 24) ? 17 : m;
  }
}

// Phase 2: exact np-replica rescore (R2-verified formula) + f64 loss partials.
__global__ __launch_bounds__(256)
void rescore_kernel(const float* __restrict__ z, const float* __restrict__ cb,
                    const float* __restrict__ e2f, const float* __restrict__ Arow,
                    const ushort* __restrict__ cand_g, const int* __restrict__ candcnt,
                    int* __restrict__ idxbuf, int* __restrict__ counts,
                    float* __restrict__ out_idx, double* __restrict__ part) {
  const int tid = threadIdx.x;
  const int n = blockIdx.x * 256 + tid;           // 256 blocks
  const int c = candcnt[n];
  double sq = 0.0;
  if (c >= 1 && c <= 16) {                        // fallback handles the rest
    const int b = n >> 10, t = n & 1023;
    const float* zb = z + (size_t)b * DT + t;
    const float A = Arow[n];
    float best = 1e30f;
    int bk = Kk;
    for (int j = 0; j < c; ++j) {
      const int k = cand_g[(size_t)n * 16 + j];
      const float* e = cb + (size_t)k * Dd;
      double acc = 0.0;
      #pragma unroll 8
      for (int d = 0; d < 128; d += 4) {
        const float4 ev = *(const float4*)(e + d);
        acc += (double)zb[(d + 0) * Tt] * (double)ev.x;
        acc += (double)zb[(d + 1) * Tt] * (double)ev.y;
        acc += (double)zb[(d + 2) * Tt] * (double)ev.z;
        acc += (double)zb[(d + 3) * Tt] * (double)ev.w;
      }
      const float m32 = (float)acc;
      const float X = __fsub_rn(A, __fmul_rn(2.0f, m32));
      const float Dq = __fadd_rn(X, e2f[k]);
      if (Dq < best || (Dq == best && k < bk)) { best = Dq; bk = k; }
    }
    idxbuf[n] = bk;
    out_idx[n] = (float)bk;
    atomicAdd(&counts[bk], 1);
    const float* ew = cb + (size_t)bk * Dd;       // winner loss pass (caches hot)
    #pragma unroll 8
    for (int d = 0; d < 128; ++d) {
      const double dif = (double)zb[d * Tt] - (double)ew[d];
      sq += dif * dif;
    }
  }
  #pragma unroll
  for (int o = 32; o > 0; o >>= 1) sq += __shfl_down(sq, o, 64);
  __shared__ double w4[4];
  if ((tid & 63) == 0) w4[tid >> 6] = sq;
  __syncthreads();
  if (tid == 0) part[blockIdx.x] = w4[0] + w4[1] + w4[2] + w4[3];
}

// Fallback: full exact scan for rows with empty/overflowed lists (expected: none).
__global__ __launch_bounds__(256)
void fallback_kernel(const float* __restrict__ z, const float* __restrict__ cb,
                     const float* __restrict__ e2f, const float* __restrict__ Arow,
                     const int* __restrict__ candcnt, int* __restrict__ idxbuf,
                     int* __restrict__ counts, float* __restrict__ out_idx,
                     double* __restrict__ part) {
  __shared__ int flags[256];
  __shared__ int nf;
  __shared__ float xrow[128];
  __shared__ float rs[256];
  __shared__ int rk[256];
  const int tid = threadIdx.x;
  const int nb = blockIdx.x * 256;                // 256 blocks
  if (tid == 0) { nf = 0; part[256 + blockIdx.x] = 0.0; }
  __syncthreads();
  const int c = candcnt[nb + tid];
  const int bad = (c < 1 || c > 16) ? 1 : 0;
  flags[tid] = bad;
  if (bad) atomicAdd(&nf, 1);
  __syncthreads();
  if (nf == 0) return;                            // fast path
  double bsum = 0.0;
  for (int rr = 0; rr < 256; ++rr) {
    if (!flags[rr]) continue;                     // block-uniform
    const int n = nb + rr;
    const int b = n >> 10, t = n & 1023;
    if (tid < 128) xrow[tid] = z[(size_t)b * DT + (size_t)tid * Tt + t];
    __syncthreads();
    const float A = Arow[n];
    float best = 1e30f;
    int bk = Kk;
    for (int kk = tid * 8; kk < tid * 8 + 8; ++kk) {
      const float* e = cb + (size_t)kk * Dd;
      double acc = 0.0;
      for (int d = 0; d < 128; d += 4) {
        const float4 ev = *(const float4*)(e + d);
        acc += (double)xrow[d + 0] * (double)ev.x;
        acc += (double)xrow[d + 1] * (double)ev.y;
        acc += (double)xrow[d + 2] * (double)ev.z;
        acc += (double)xrow[d + 3] * (double)ev.w;
      }
      const float m32 = (float)acc;
      const float Dq = __fadd_rn(__fsub_rn(A, __fmul_rn(2.0f, m32)), e2f[kk]);
      if (Dq < best || (Dq == best && kk < bk)) { best = Dq; bk = kk; }
    }
    rs[tid] = best;
    rk[tid] = bk;
    __syncthreads();
    for (int o = 128; o > 0; o >>= 1) {
      if (tid < o) {
        if (rs[tid + o] < rs[tid] || (rs[tid + o] == rs[tid] && rk[tid + o] < rk[tid])) {
          rs[tid] = rs[tid + o];
          rk[tid] = rk[tid + o];
        }
      }
      __syncthreads();
    }
    if (tid == 0) {
      const int w = rk[0];
      idxbuf[n] = w;
      out_idx[n] = (float)w;
      atomicAdd(&counts[w], 1);
      const float* ew = cb + (size_t)w * Dd;
      for (int d = 0; d < 128; ++d) {
        const double dif = (double)xrow[d] - (double)ew[d];
        bsum += dif * dif;
      }
    }
    __syncthreads();
  }
  if (tid == 0) part[256 + blockIdx.x] = bsum;
}

// Gather z_q into (B,D,T) layout (z_q_st == z_q in value; no z read needed).
__global__ __launch_bounds__(256)
void gather_kernel(const float* __restrict__ cb, const int* __restrict__ idxbuf,
                   float* __restrict__ out0) {
  const int tid = threadIdx.x;
  const size_t o0 = ((size_t)blockIdx.x * 256 + tid) * 8;  // 4096 blocks
  const int b = (int)(o0 >> 17);
  const int dt = (int)(o0 & (size_t)(DT - 1));
  const int d = dt >> 10;
  const int t = dt & 1023;
  const int n = (b << 10) + t;
  float q[8];
  #pragma unroll
  for (int j = 0; j < 8; ++j) q[j] = cb[(size_t)idxbuf[n + j] * Dd + d];
  *(float4*)(out0 + o0)     = make_float4(q[0], q[1], q[2], q[3]);
  *(float4*)(out0 + o0 + 4) = make_float4(q[4], q[5], q[6], q[7]);
}

__global__ __launch_bounds__(256)
void finalize_kernel(const int* __restrict__ counts, const double* __restrict__ part,
                     float* __restrict__ out) {
  const int tid = threadIdx.x;
  __shared__ double red[256];
  double s = 0.0;
  for (int i = tid; i < 512; i += 256) s += part[i];
  red[tid] = s;
  __syncthreads();
  for (int o = 128; o > 0; o >>= 1) {
    if (tid < o) red[tid] += red[tid + o];
    __syncthreads();
  }
  const double loss = red[0];
  __syncthreads();
  double e = 0.0;
  for (int k = tid; k < 2048; k += 256) {
    const double p = (double)counts[k] / 65536.0;
    e += p * log(p + 1e-10);
  }
  red[tid] = e;
  __syncthreads();
  for (int o = 128; o > 0; o >>= 1) {
    if (tid < o) red[tid] += red[tid + o];
    __syncthreads();
  }
  if (tid == 0) {
    out[8388608] = (float)(0.25 * loss / 8388608.0);
    out[8388609] = (float)exp(-red[0]);
  }
}

extern "C" void kernel_launch(void* const* d_in, const int* in_sizes, int n_in,
                              void* d_out, int out_size, void* d_ws, size_t ws_size,
                              hipStream_t stream) {
  const float* z = (const float*)d_in[0];      // (B, D, T) fp32
  const float* cb = (const float*)d_in[1];     // (K, D) fp32
  float* out = (float*)d_out;                  // [z_q (8388608) | loss | perp | idx (65536)]
  char* ws = (char*)d_ws;
  ushort* cbh    = (ushort*)ws;
  float* e2f     = (float*)(ws + 524288);
  float* Arow    = (float*)(ws + 532480);
  int* idxbuf    = (int*)(ws + 794624);
  int* counts    = (int*)(ws + 1056768);
  double* part   = (double*)(ws + 1064960);
  ushort* cand_g = (ushort*)(ws + 1069056);
  int* candcnt   = (int*)(ws + 3166208);

  hipLaunchKernelGGL(setup_kernel,    dim3(1288), dim3(256), 0, stream, cb, z, cbh, e2f, Arow, counts);
  hipLaunchKernelGGL(score_kernel,    dim3(512),  dim3(256), 0, stream, z, cbh, e2f, Arow,
                     cand_g, candcnt);
  hipLaunchKernelGGL(rescore_kernel,  dim3(256),  dim3(256), 0, stream, z, cb, e2f, Arow,
                     cand_g, candcnt, idxbuf, counts, out + 8388610, part);
  hipLaunchKernelGGL(fallback_kernel, dim3(256),  dim3(256), 0, stream, z, cb, e2f, Arow,
                     candcnt, idxbuf, counts, out + 8388610, part);
  hipLaunchKernelGGL(gather_kernel,   dim3(4096), dim3(256), 0, stream, cb, idxbuf, out);
  hipLaunchKernelGGL(finalize_kernel, dim3(1),    dim3(256), 0, stream, counts, part, out);
}

// Round 2
// 301.296 us; speedup vs baseline: 3.1182x; 3.1182x over previous
//
#include <hip/hip_runtime.h>
#include <math.h>

#define Dd 128
#define Tt 1024
#define Kk 2048
#define Nn 65536
#define DT 131072  // Dd*Tt

typedef __attribute__((ext_vector_type(8))) short short8;
typedef __attribute__((ext_vector_type(4))) float float4v;

// ws layout (bytes):
//   cbh     @ 0        : ushort[262144] = 524288   (bf16 hi plane of codebook, [k][d])
//   e2f     @ 524288   : float[2048]    = 8192     (np-replica fp32 ||e||^2)
//   Arow    @ 532480   : float[65536]   = 262144   (np-replica fp32 ||x||^2)
//   idxbuf  @ 794624   : int[65536]     = 262144
//   counts  @ 1056768  : int[2048]      = 8192
//   part    @ 1064960  : double[512]    = 4096
//   cand_g  @ 1069056  : ushort[65536*16] = 2097152
//   candcnt @ 3166208  : int[65536]     = 262144
// total 3428352 B (~3.43 MB)

__device__ __forceinline__ void gload16(const void* g, void* l) {
  // 16B global->LDS direct copy; LDS dest = wave-uniform base + lane*16.
  __builtin_amdgcn_global_load_lds(
      (const __attribute__((address_space(1))) unsigned int*)g,
      (__attribute__((address_space(3))) unsigned int*)l, 16, 0, 0);
}

// Fused setup: bf16-hi split of codebook + zero histogram (blocks 0..1023),
// np-replica fp32 ||e||^2 (blocks 1024..1031), np-replica fp32 ||x||^2
// (blocks 1032..1287). numpy pairwise order for n=128: 8 accumulators,
// sequential i, combine ((r0+r1)+(r2+r3))+((r4+r5)+(r6+r7)); __f*_rn blocks
// FMA contraction so each square rounds like numpy's flat*flat.
__global__ __launch_bounds__(256)
void setup_kernel(const float* __restrict__ cb, const float* __restrict__ z,
                  ushort* __restrict__ cbh, float* __restrict__ e2f,
                  float* __restrict__ Arow, int* __restrict__ counts) {
  const int bid = blockIdx.x, tid = threadIdx.x;
  if (bid < 1024) {
    const int g = bid * 256 + tid;                // 262144 codebook elems
    const float v = cb[g];
    const unsigned u = __float_as_uint(v);
    const unsigned hb = (u + 0x7FFFu + ((u >> 16) & 1u)) & 0xFFFF0000u;  // RNE bf16
    cbh[g] = (ushort)(hb >> 16);
    if (g < Kk) counts[g] = 0;
  } else if (bid < 1032) {
    const int k = (bid - 1024) * 256 + tid;       // 2048 codes
    const float* p = cb + (size_t)k * Dd;
    float r[8];
    #pragma unroll
    for (int j = 0; j < 8; ++j) r[j] = __fmul_rn(p[j], p[j]);
    for (int i = 1; i < 16; ++i) {
      #pragma unroll
      for (int j = 0; j < 8; ++j) {
        const float v = p[8 * i + j];
        r[j] = __fadd_rn(r[j], __fmul_rn(v, v));
      }
    }
    e2f[k] = __fadd_rn(__fadd_rn(__fadd_rn(r[0], r[1]), __fadd_rn(r[2], r[3])),
                       __fadd_rn(__fadd_rn(r[4], r[5]), __fadd_rn(r[6], r[7])));
  } else {
    const int g = (bid - 1032) * 256 + tid;       // 65536 rows
    const int b = g >> 10, t = g & 1023;
    const float* p = z + (size_t)b * DT + t;      // x_d = p[d*Tt]
    float r[8];
    #pragma unroll
    for (int j = 0; j < 8; ++j) {
      const float v = p[j * Tt];
      r[j] = __fmul_rn(v, v);
    }
    for (int i = 1; i < 16; ++i) {
      #pragma unroll
      for (int j = 0; j < 8; ++j) {
        const float v = p[(8 * i + j) * Tt];
        r[j] = __fadd_rn(r[j], __fmul_rn(v, v));
      }
    }
    Arow[g] = __fadd_rn(__fadd_rn(__fadd_rn(r[0], r[1]), __fadd_rn(r[2], r[3])),
                        __fadd_rn(__fadd_rn(r[4], r[5]), __fadd_rn(r[6], r[7])));
  }
}

// Phase 1: two-sweep hi-plane bf16 MFMA scoring, A-in-registers.
// 128 rows/block (512 blocks), 4 waves; EACH wave owns all 128 rows and a
// 16-col slice of each 64-code chunk: per chunk per wave = 4 ds_read_b128
// (B only) + 32 MFMA. A (z rows, bf16-hi) lives in 128 VGPRs for the whole
// kernel. Chunks staged double-buffered via global_load_lds (16B), source
// pre-swizzled so LDS stays linear; granule-XOR swizzle kills bank
// conflicts on the B reads.
// Sweep A: per-lane running min -> shfl-reduce over 16 cols -> LDS reduce
// over 4 waves -> exact row-global min m. Sweep B: bitwise-identical
// recompute, append codes with s < m + marg_row (marg_row =
// 8.7e-5*sqrt(Arow)+1e-4, same deterministic bound as the verified
// baseline). Cap 16; candcnt>16 -> exact fallback (expected: none).
__global__ __launch_bounds__(256, 2)
void score_kernel(const float* __restrict__ z, const ushort* __restrict__ cbh,
                  const float* __restrict__ e2f, const float* __restrict__ Arow,
                  ushort* __restrict__ cand_g, int* __restrict__ candcnt) {
  __shared__ __attribute__((aligned(16))) ushort eh[16384]; // 32KB: zh (prologue) -> 2x16KB chunk dbuf
  __shared__ float e2s[2048];        // 8KB
  __shared__ float margL[128];
  __shared__ float sredA[512];       // [row][wv]
  __shared__ float thrF[128];
  __shared__ int cntL[128];
  __shared__ ushort candL[128 * 16]; // 4KB

  const int tid = threadIdx.x;
  const int n0 = blockIdx.x * 128;               // 512 blocks
  const int b = n0 >> 10, t0 = n0 & 1023;
  const float* zb = z + (size_t)b * DT + t0;
  const int lane = tid & 63, wv = tid >> 6;
  const int col = lane & 15, quad = lane >> 4;

  // ---- prologue: stage z hi plane (128 rows x 128 d, 16B-granule swizzled) ----
  {
    const int i = tid & 127;          // row in block
    const int half = tid >> 7;        // 0/1
    #pragma unroll
    for (int g8 = 0; g8 < 8; ++g8) {
      const int gran = half * 8 + g8;
      short8 w;
      #pragma unroll
      for (int j = 0; j < 8; ++j) {
        const int d = gran * 8 + j;
        const float v = zb[d * Tt + i];            // coalesced over i
        const unsigned u = __float_as_uint(v);
        const unsigned hb = (u + 0x7FFFu + ((u >> 16) & 1u)) & 0xFFFF0000u;
        w[j] = (short)(hb >> 16);
      }
      *(short8*)&eh[i * 128 + ((gran ^ (i & 15)) << 3)] = w;
    }
  }
  #pragma unroll
  for (int j = 0; j < 8; ++j) e2s[tid + 256 * j] = e2f[tid + 256 * j];
  if (tid < 128) {
    margL[tid] = 8.7e-5f * sqrtf(Arow[n0 + tid]) + 1.0e-4f;
    cntL[tid] = 0;
  }
  __syncthreads();

  // ---- A fragments into registers (all 128 rows per wave, K=128) ----
  short8 afr[8][4];
  #pragma unroll
  for (int rt = 0; rt < 8; ++rt)
    #pragma unroll
    for (int ks = 0; ks < 4; ++ks) {
      const int rw = rt * 16 + col;               // rw&15 == col
      afr[rt][ks] = *(const short8*)&eh[rw * 128 + (((ks * 4 + quad) ^ col) << 3)];
    }
  __syncthreads();  // all zh reads done before chunk staging overwrites

  // stage chunk 0 into buf 0 (source pre-swizzled, LDS linear)
  #pragma unroll
  for (int j = 0; j < 4; ++j) {
    const int gidx = j * 256 + wv * 64 + lane;
    const int c = gidx >> 4;
    const int kb = (gidx & 15) ^ (c & 15);
    gload16(cbh + (((size_t)c) << 7) + (kb << 3), &eh[(j * 256 + wv * 64) * 8]);
  }

  const float4v vzero = {0.f, 0.f, 0.f, 0.f};
  float rmin[32];
  #pragma unroll
  for (int sl = 0; sl < 32; ++sl) rmin[sl] = 1e30f;

  // ---- Sweep A: exact row-global min over bf16-hi scores ----
  for (int it = 0; it < 32; ++it) {
    __syncthreads();                 // drains staged chunk for this iter
    {
      const int nc = (it + 1) & 31;  // it=31 pre-stages chunk 0 for sweep B
      const int nb = ((it + 1) & 1) * 8192;
      #pragma unroll
      for (int j = 0; j < 4; ++j) {
        const int gidx = j * 256 + wv * 64 + lane;
        const int c = gidx >> 4;
        const int kb = (gidx & 15) ^ (c & 15);
        gload16(cbh + (((size_t)(nc * 64 + c)) << 7) + (kb << 3),
                &eh[nb + (j * 256 + wv * 64) * 8]);
      }
    }
    const ushort* eb = eh + (it & 1) * 8192;
    float4v acc[8];
    #pragma unroll
    for (int rt = 0; rt < 8; ++rt) acc[rt] = vzero;
    #pragma unroll
    for (int ks = 0; ks < 4; ++ks) {
      const short8 bb = *(const short8*)&eb[(wv * 16 + col) * 128 + (((ks * 4 + quad) ^ col) << 3)];
      #pragma unroll
      for (int rt = 0; rt < 8; ++rt)
        acc[rt] = __builtin_amdgcn_mfma_f32_16x16x32_bf16(afr[rt][ks], bb, acc[rt], 0, 0, 0);
    }
    const float e2v = e2s[it * 64 + wv * 16 + col];
    #pragma unroll
    for (int rt = 0; rt < 8; ++rt)
      #pragma unroll
      for (int r = 0; r < 4; ++r) {
        const float s = fmaf(-2.0f, acc[rt][r], e2v);
        rmin[rt * 4 + r] = fminf(rmin[rt * 4 + r], s);
      }
  }

  // ---- exact row-global min reduce: 16 cols (shfl) x 4 waves (LDS) ----
  #pragma unroll
  for (int sl = 0; sl < 32; ++sl) {
    float v = rmin[sl];
    v = fminf(v, __shfl_xor(v, 1, 64));
    v = fminf(v, __shfl_xor(v, 2, 64));
    v = fminf(v, __shfl_xor(v, 4, 64));
    v = fminf(v, __shfl_xor(v, 8, 64));
    rmin[sl] = v;
  }
  if (col == 0) {
    #pragma unroll
    for (int sl = 0; sl < 32; ++sl) {
      const int rw = (sl >> 2) * 16 + quad * 4 + (sl & 3);
      sredA[rw * 4 + wv] = rmin[sl];
    }
  }
  __syncthreads();
  if (tid < 128) {
    const float m = fminf(fminf(sredA[tid * 4], sredA[tid * 4 + 1]),
                          fminf(sredA[tid * 4 + 2], sredA[tid * 4 + 3]));
    thrF[tid] = m + margL[tid];
  }
  __syncthreads();
  #pragma unroll
  for (int sl = 0; sl < 32; ++sl)       // reuse rmin regs as per-slot thresholds
    rmin[sl] = thrF[(sl >> 2) * 16 + quad * 4 + (sl & 3)];

  // ---- Sweep B: identical recompute, exact-threshold append ----
  for (int it = 0; it < 32; ++it) {
    __syncthreads();
    if (it < 31) {
      const int nc = it + 1;
      const int nb = ((it + 1) & 1) * 8192;
      #pragma unroll
      for (int j = 0; j < 4; ++j) {
        const int gidx = j * 256 + wv * 64 + lane;
        const int c = gidx >> 4;
        const int kb = (gidx & 15) ^ (c & 15);
        gload16(cbh + (((size_t)(nc * 64 + c)) << 7) + (kb << 3),
                &eh[nb + (j * 256 + wv * 64) * 8]);
      }
    }
    const ushort* eb = eh + (it & 1) * 8192;
    float4v acc[8];
    #pragma unroll
    for (int rt = 0; rt < 8; ++rt) acc[rt] = vzero;
    #pragma unroll
    for (int ks = 0; ks < 4; ++ks) {
      const short8 bb = *(const short8*)&eb[(wv * 16 + col) * 128 + (((ks * 4 + quad) ^ col) << 3)];
      #pragma unroll
      for (int rt = 0; rt < 8; ++rt)
        acc[rt] = __builtin_amdgcn_mfma_f32_16x16x32_bf16(afr[rt][ks], bb, acc[rt], 0, 0, 0);
    }
    const int cbase = it * 64 + wv * 16 + col;
    const float e2v = e2s[cbase];
    #pragma unroll
    for (int rt = 0; rt < 8; ++rt)
      #pragma unroll
      for (int r = 0; r < 4; ++r) {
        const float s = fmaf(-2.0f, acc[rt][r], e2v);
        if (s < rmin[rt * 4 + r]) {
          const int rw = rt * 16 + quad * 4 + r;
          const int pos = atomicAdd(&cntL[rw], 1);
          if (pos < 16) candL[rw * 16 + pos] = (ushort)cbase;
        }
      }
  }
  __syncthreads();
  if (tid < 128) {
    const int n = n0 + tid;
    candcnt[n] = cntL[tid];
    uint4* dst = (uint4*)(cand_g + (size_t)n * 16);
    const uint4* src = (const uint4*)(candL + tid * 16);
    dst[0] = src[0];
    dst[1] = src[1];
  }
}

// Phase 2: exact np-replica rescore (R2-verified formula) + f64 loss partials.
__global__ __launch_bounds__(256)
void rescore_kernel(const float* __restrict__ z, const float* __restrict__ cb,
                    const float* __restrict__ e2f, const float* __restrict__ Arow,
                    const ushort* __restrict__ cand_g, const int* __restrict__ candcnt,
                    int* __restrict__ idxbuf, int* __restrict__ counts,
                    float* __restrict__ out_idx, double* __restrict__ part) {
  const int tid = threadIdx.x;
  const int n = blockIdx.x * 256 + tid;           // 256 blocks
  const int c = candcnt[n];
  double sq = 0.0;
  if (c >= 1 && c <= 16) {                        // fallback handles the rest
    const int b = n >> 10, t = n & 1023;
    const float* zb = z + (size_t)b * DT + t;
    const float A = Arow[n];
    float best = 1e30f;
    int bk = Kk;
    for (int j = 0; j < c; ++j) {
      const int k = cand_g[(size_t)n * 16 + j];
      const float* e = cb + (size_t)k * Dd;
      double acc = 0.0;
      #pragma unroll 8
      for (int d = 0; d < 128; d += 4) {
        const float4 ev = *(const float4*)(e + d);
        acc += (double)zb[(d + 0) * Tt] * (double)ev.x;
        acc += (double)zb[(d + 1) * Tt] * (double)ev.y;
        acc += (double)zb[(d + 2) * Tt] * (double)ev.z;
        acc += (double)zb[(d + 3) * Tt] * (double)ev.w;
      }
      const float m32 = (float)acc;
      const float X = __fsub_rn(A, __fmul_rn(2.0f, m32));
      const float Dq = __fadd_rn(X, e2f[k]);
      if (Dq < best || (Dq == best && k < bk)) { best = Dq; bk = k; }
    }
    idxbuf[n] = bk;
    out_idx[n] = (float)bk;
    atomicAdd(&counts[bk], 1);
    const float* ew = cb + (size_t)bk * Dd;       // winner loss pass (caches hot)
    #pragma unroll 8
    for (int d = 0; d < 128; ++d) {
      const double dif = (double)zb[d * Tt] - (double)ew[d];
      sq += dif * dif;
    }
  }
  #pragma unroll
  for (int o = 32; o > 0; o >>= 1) sq += __shfl_down(sq, o, 64);
  __shared__ double w4[4];
  if ((tid & 63) == 0) w4[tid >> 6] = sq;
  __syncthreads();
  if (tid == 0) part[blockIdx.x] = w4[0] + w4[1] + w4[2] + w4[3];
}

// Fallback: full exact scan for rows with empty/overflowed lists (expected: none).
__global__ __launch_bounds__(256)
void fallback_kernel(const float* __restrict__ z, const float* __restrict__ cb,
                     const float* __restrict__ e2f, const float* __restrict__ Arow,
                     const int* __restrict__ candcnt, int* __restrict__ idxbuf,
                     int* __restrict__ counts, float* __restrict__ out_idx,
                     double* __restrict__ part) {
  __shared__ int flags[256];
  __shared__ int nf;
  __shared__ float xrow[128];
  __shared__ float rs[256];
  __shared__ int rk[256];
  const int tid = threadIdx.x;
  const int nb = blockIdx.x * 256;                // 256 blocks
  if (tid == 0) { nf = 0; part[256 + blockIdx.x] = 0.0; }
  __syncthreads();
  const int c = candcnt[nb + tid];
  const int bad = (c < 1 || c > 16) ? 1 : 0;
  flags[tid] = bad;
  if (bad) atomicAdd(&nf, 1);
  __syncthreads();
  if (nf == 0) return;                            // fast path
  double bsum = 0.0;
  for (int rr = 0; rr < 256; ++rr) {
    if (!flags[rr]) continue;                     // block-uniform
    const int n = nb + rr;
    const int b = n >> 10, t = n & 1023;
    if (tid < 128) xrow[tid] = z[(size_t)b * DT + (size_t)tid * Tt + t];
    __syncthreads();
    const float A = Arow[n];
    float best = 1e30f;
    int bk = Kk;
    for (int kk = tid * 8; kk < tid * 8 + 8; ++kk) {
      const float* e = cb + (size_t)kk * Dd;
      double acc = 0.0;
      for (int d = 0; d < 128; d += 4) {
        const float4 ev = *(const float4*)(e + d);
        acc += (double)xrow[d + 0] * (double)ev.x;
        acc += (double)xrow[d + 1] * (double)ev.y;
        acc += (double)xrow[d + 2] * (double)ev.z;
        acc += (double)xrow[d + 3] * (double)ev.w;
      }
      const float m32 = (float)acc;
      const float Dq = __fadd_rn(__fsub_rn(A, __fmul_rn(2.0f, m32)), e2f[kk]);
      if (Dq < best || (Dq == best && kk < bk)) { best = Dq; bk = kk; }
    }
    rs[tid] = best;
    rk[tid] = bk;
    __syncthreads();
    for (int o = 128; o > 0; o >>= 1) {
      if (tid < o) {
        if (rs[tid + o] < rs[tid] || (rs[tid + o] == rs[tid] && rk[tid + o] < rk[tid])) {
          rs[tid] = rs[tid + o];
          rk[tid] = rk[tid + o];
        }
      }
      __syncthreads();
    }
    if (tid == 0) {
      const int w = rk[0];
      idxbuf[n] = w;
      out_idx[n] = (float)w;
      atomicAdd(&counts[w], 1);
      const float* ew = cb + (size_t)w * Dd;
      for (int d = 0; d < 128; ++d) {
        const double dif = (double)xrow[d] - (double)ew[d];
        bsum += dif * dif;
      }
    }
    __syncthreads();
  }
  if (tid == 0) part[256 + blockIdx.x] = bsum;
}

// Gather z_q into (B,D,T) layout (z_q_st == z_q in value; no z read needed).
__global__ __launch_bounds__(256)
void gather_kernel(const float* __restrict__ cb, const int* __restrict__ idxbuf,
                   float* __restrict__ out0) {
  const int tid = threadIdx.x;
  const size_t o0 = ((size_t)blockIdx.x * 256 + tid) * 8;  // 4096 blocks
  const int b = (int)(o0 >> 17);
  const int dt = (int)(o0 & (size_t)(DT - 1));
  const int d = dt >> 10;
  const int t = dt & 1023;
  const int n = (b << 10) + t;
  float q[8];
  #pragma unroll
  for (int j = 0; j < 8; ++j) q[j] = cb[(size_t)idxbuf[n + j] * Dd + d];
  *(float4*)(out0 + o0)     = make_float4(q[0], q[1], q[2], q[3]);
  *(float4*)(out0 + o0 + 4) = make_float4(q[4], q[5], q[6], q[7]);
}

__global__ __launch_bounds__(256)
void finalize_kernel(const int* __restrict__ counts, const double* __restrict__ part,
                     float* __restrict__ out) {
  const int tid = threadIdx.x;
  __shared__ double red[256];
  double s = 0.0;
  for (int i = tid; i < 512; i += 256) s += part[i];
  red[tid] = s;
  __syncthreads();
  for (int o = 128; o > 0; o >>= 1) {
    if (tid < o) red[tid] += red[tid + o];
    __syncthreads();
  }
  const double loss = red[0];
  __syncthreads();
  double e = 0.0;
  for (int k = tid; k < 2048; k += 256) {
    const double p = (double)counts[k] / 65536.0;
    e += p * log(p + 1e-10);
  }
  red[tid] = e;
  __syncthreads();
  for (int o = 128; o > 0; o >>= 1) {
    if (tid < o) red[tid] += red[tid + o];
    __syncthreads();
  }
  if (tid == 0) {
    out[8388608] = (float)(0.25 * loss / 8388608.0);
    out[8388609] = (float)exp(-red[0]);
  }
}

extern "C" void kernel_launch(void* const* d_in, const int* in_sizes, int n_in,
                              void* d_out, int out_size, void* d_ws, size_t ws_size,
                              hipStream_t stream) {
  const float* z = (const float*)d_in[0];      // (B, D, T) fp32
  const float* cb = (const float*)d_in[1];     // (K, D) fp32
  float* out = (float*)d_out;                  // [z_q (8388608) | loss | perp | idx (65536)]
  char* ws = (char*)d_ws;
  ushort* cbh    = (ushort*)ws;
  float* e2f     = (float*)(ws + 524288);
  float* Arow    = (float*)(ws + 532480);
  int* idxbuf    = (int*)(ws + 794624);
  int* counts    = (int*)(ws + 1056768);
  double* part   = (double*)(ws + 1064960);
  ushort* cand_g = (ushort*)(ws + 1069056);
  int* candcnt   = (int*)(ws + 3166208);

  hipLaunchKernelGGL(setup_kernel,    dim3(1288), dim3(256), 0, stream, cb, z, cbh, e2f, Arow, counts);
  hipLaunchKernelGGL(score_kernel,    dim3(512),  dim3(256), 0, stream, z, cbh, e2f, Arow,
                     cand_g, candcnt);
  hipLaunchKernelGGL(rescore_kernel,  dim3(256),  dim3(256), 0, stream, z, cb, e2f, Arow,
                     cand_g, candcnt, idxbuf, counts, out + 8388610, part);
  hipLaunchKernelGGL(fallback_kernel, dim3(256),  dim3(256), 0, stream, z, cb, e2f, Arow,
                     candcnt, idxbuf, counts, out + 8388610, part);
  hipLaunchKernelGGL(gather_kernel,   dim3(4096), dim3(256), 0, stream, cb, idxbuf, out);
  hipLaunchKernelGGL(finalize_kernel, dim3(1),    dim3(256), 0, stream, counts, part, out);
}

// Round 3
// 283.477 us; speedup vs baseline: 3.3142x; 1.0629x over previous
//
#include <hip/hip_runtime.h>
#include <math.h>

#define Dd 128
#define Tt 1024
#define Kk 2048
#define Nn 65536
#define DT 131072  // Dd*Tt

typedef __attribute__((ext_vector_type(8))) short short8;
typedef __attribute__((ext_vector_type(4))) float float4v;

// ws layout (bytes):
//   cbh     @ 0        : ushort[262144] = 524288   (bf16 hi plane of codebook, [k][d])
//   e2f     @ 524288   : float[2048]    = 8192     (np-replica fp32 ||e||^2)
//   Arow    @ 532480   : float[65536]   = 262144   (np-replica fp32 ||x||^2)
//   idxbuf  @ 794624   : int[65536]     = 262144
//   counts  @ 1056768  : int[2048]      = 8192
//   part    @ 1064960  : double[512]    = 4096
//   cand_g  @ 1069056  : ushort[65536*16] = 2097152
//   candcnt @ 3166208  : int[65536]     = 262144
// total 3428352 B (~3.43 MB)

// Fused setup: bf16-hi split of codebook + zero histogram (blocks 0..1023),
// np-replica fp32 ||e||^2 (blocks 1024..1031), np-replica fp32 ||x||^2
// (blocks 1032..1287). numpy pairwise order for n=128: 8 accumulators,
// sequential i, combine ((r0+r1)+(r2+r3))+((r4+r5)+(r6+r7)); __f*_rn blocks
// FMA contraction so each square rounds like numpy's flat*flat.
__global__ __launch_bounds__(256)
void setup_kernel(const float* __restrict__ cb, const float* __restrict__ z,
                  ushort* __restrict__ cbh, float* __restrict__ e2f,
                  float* __restrict__ Arow, int* __restrict__ counts) {
  const int bid = blockIdx.x, tid = threadIdx.x;
  if (bid < 1024) {
    const int g = bid * 256 + tid;                // 262144 codebook elems
    const float v = cb[g];
    const unsigned u = __float_as_uint(v);
    const unsigned hb = (u + 0x7FFFu + ((u >> 16) & 1u)) & 0xFFFF0000u;  // RNE bf16
    cbh[g] = (ushort)(hb >> 16);
    if (g < Kk) counts[g] = 0;
  } else if (bid < 1032) {
    const int k = (bid - 1024) * 256 + tid;       // 2048 codes
    const float* p = cb + (size_t)k * Dd;
    float r[8];
    #pragma unroll
    for (int j = 0; j < 8; ++j) r[j] = __fmul_rn(p[j], p[j]);
    for (int i = 1; i < 16; ++i) {
      #pragma unroll
      for (int j = 0; j < 8; ++j) {
        const float v = p[8 * i + j];
        r[j] = __fadd_rn(r[j], __fmul_rn(v, v));
      }
    }
    e2f[k] = __fadd_rn(__fadd_rn(__fadd_rn(r[0], r[1]), __fadd_rn(r[2], r[3])),
                       __fadd_rn(__fadd_rn(r[4], r[5]), __fadd_rn(r[6], r[7])));
  } else {
    const int g = (bid - 1032) * 256 + tid;       // 65536 rows
    const int b = g >> 10, t = g & 1023;
    const float* p = z + (size_t)b * DT + t;      // x_d = p[d*Tt]
    float r[8];
    #pragma unroll
    for (int j = 0; j < 8; ++j) {
      const float v = p[j * Tt];
      r[j] = __fmul_rn(v, v);
    }
    for (int i = 1; i < 16; ++i) {
      #pragma unroll
      for (int j = 0; j < 8; ++j) {
        const float v = p[(8 * i + j) * Tt];
        r[j] = __fadd_rn(r[j], __fmul_rn(v, v));
      }
    }
    Arow[g] = __fadd_rn(__fadd_rn(__fadd_rn(r[0], r[1]), __fadd_rn(r[2], r[3])),
                        __fadd_rn(__fadd_rn(r[4], r[5]), __fadd_rn(r[6], r[7])));
  }
}

// Phase 1: two-sweep hi-plane bf16 MFMA scoring, BARRIER-FREE main loops.
// 128 rows/block (512 blocks), 4 waves; each wave owns all 128 rows and a
// 16-col slice of each 64-code chunk. A (z rows, bf16-hi) lives in VGPRs for
// the whole kernel (staged once via LDS transpose in the prologue). B is
// loaded DIRECTLY global->VGPR (codebook hi-plane = 512 KB, L2-resident per
// XCD; 8 waves/CU stream the same chunk -> L1-served). One base-pointer bump
// + 4 imm-offset dwordx4 loads per iter; 1-deep register prefetch. No LDS
// staging, no ds_read, no __syncthreads in the loops -> compiler pipelines
// loads freely across iterations.
// Sweep A: per-lane running min -> shfl over 16 cols -> LDS reduce over 4
// waves -> exact row-global min m. Sweep B: bitwise-identical recompute,
// append codes with s < m + marg_row (marg_row = 8.7e-5*sqrt(Arow)+1e-4,
// same deterministic bound as the verified baseline). Cap 16; candcnt>16 ->
// exact fallback (expected: none).
__global__ __launch_bounds__(256, 2)
void score_kernel(const float* __restrict__ z, const ushort* __restrict__ cbh,
                  const float* __restrict__ e2f, const float* __restrict__ Arow,
                  ushort* __restrict__ cand_g, int* __restrict__ candcnt) {
  __shared__ __attribute__((aligned(16))) ushort zh[16384]; // 32KB z hi plane
  __shared__ float margL[128];
  __shared__ float sredA[512];       // [row][wv]
  __shared__ float thrF[128];
  __shared__ int cntL[128];
  __shared__ ushort candL[128 * 16]; // 4KB

  const int tid = threadIdx.x;
  const int n0 = blockIdx.x * 128;               // 512 blocks
  const int b = n0 >> 10, t0 = n0 & 1023;
  const float* zb = z + (size_t)b * DT + t0;
  const int lane = tid & 63, wv = tid >> 6;
  const int col = lane & 15, quad = lane >> 4;

  // ---- prologue: stage z hi plane (128 rows x 128 d, 16B-granule swizzled) ----
  {
    const int i = tid & 127;          // row in block
    const int half = tid >> 7;        // 0/1
    #pragma unroll
    for (int g8 = 0; g8 < 8; ++g8) {
      const int gran = half * 8 + g8;
      short8 w;
      #pragma unroll
      for (int j = 0; j < 8; ++j) {
        const int d = gran * 8 + j;
        const float v = zb[d * Tt + i];            // coalesced over i
        const unsigned u = __float_as_uint(v);
        const unsigned hb = (u + 0x7FFFu + ((u >> 16) & 1u)) & 0xFFFF0000u;
        w[j] = (short)(hb >> 16);
      }
      *(short8*)&zh[i * 128 + ((gran ^ (i & 15)) << 3)] = w;
    }
  }
  if (tid < 128) {
    margL[tid] = 8.7e-5f * sqrtf(Arow[n0 + tid]) + 1.0e-4f;
    cntL[tid] = 0;
  }
  __syncthreads();

  // ---- A fragments into registers (all 128 rows per wave, K=128) ----
  short8 afr[8][4];
  #pragma unroll
  for (int rt = 0; rt < 8; ++rt)
    #pragma unroll
    for (int ks = 0; ks < 4; ++ks) {
      const int rw = rt * 16 + col;               // rw&15 == col
      afr[rt][ks] = *(const short8*)&zh[rw * 128 + (((ks * 4 + quad) ^ col) << 3)];
    }

  // per-lane B base: code (wv*16+col), 16B granule quad; ks -> +64B imm
  const ushort* const bp0 = cbh + (((size_t)(wv * 16 + col)) << 7) + (quad << 3);
  const float* const ep0 = e2f + wv * 16 + col;

  const float4v vzero = {0.f, 0.f, 0.f, 0.f};
  float rmin[32];
  #pragma unroll
  for (int sl = 0; sl < 32; ++sl) rmin[sl] = 1e30f;

  // ---- Sweep A: exact row-global min over bf16-hi scores (barrier-free) ----
  {
    const ushort* bp = bp0;
    const float* ep = ep0;
    short8 bb[4];
    #pragma unroll
    for (int ks = 0; ks < 4; ++ks) bb[ks] = *(const short8*)(bp + ks * 32);
    float e2v = *ep;
    for (int it = 0; it < 32; ++it) {
      const int adv = (it < 31) ? 8192 : 0;       // prefetch next chunk (clamped)
      const int eadv = (it < 31) ? 64 : 0;
      short8 nb[4];
      #pragma unroll
      for (int ks = 0; ks < 4; ++ks) nb[ks] = *(const short8*)(bp + adv + ks * 32);
      const float ne2 = ep[eadv];
      float4v acc[8];
      #pragma unroll
      for (int rt = 0; rt < 8; ++rt) acc[rt] = vzero;
      #pragma unroll
      for (int ks = 0; ks < 4; ++ks)
        #pragma unroll
        for (int rt = 0; rt < 8; ++rt)
          acc[rt] = __builtin_amdgcn_mfma_f32_16x16x32_bf16(afr[rt][ks], bb[ks], acc[rt], 0, 0, 0);
      #pragma unroll
      for (int rt = 0; rt < 8; ++rt)
        #pragma unroll
        for (int r = 0; r < 4; ++r) {
          const float s = fmaf(-2.0f, acc[rt][r], e2v);
          rmin[rt * 4 + r] = fminf(rmin[rt * 4 + r], s);
        }
      #pragma unroll
      for (int ks = 0; ks < 4; ++ks) bb[ks] = nb[ks];
      e2v = ne2;
      bp += 8192;
      ep += 64;
    }
  }

  // ---- exact row-global min reduce: 16 cols (shfl) x 4 waves (LDS) ----
  #pragma unroll
  for (int sl = 0; sl < 32; ++sl) {
    float v = rmin[sl];
    v = fminf(v, __shfl_xor(v, 1, 64));
    v = fminf(v, __shfl_xor(v, 2, 64));
    v = fminf(v, __shfl_xor(v, 4, 64));
    v = fminf(v, __shfl_xor(v, 8, 64));
    rmin[sl] = v;
  }
  if (col == 0) {
    #pragma unroll
    for (int sl = 0; sl < 32; ++sl) {
      const int rw = (sl >> 2) * 16 + quad * 4 + (sl & 3);
      sredA[rw * 4 + wv] = rmin[sl];
    }
  }
  __syncthreads();
  if (tid < 128) {
    const float m = fminf(fminf(sredA[tid * 4], sredA[tid * 4 + 1]),
                          fminf(sredA[tid * 4 + 2], sredA[tid * 4 + 3]));
    thrF[tid] = m + margL[tid];
  }
  __syncthreads();
  #pragma unroll
  for (int sl = 0; sl < 32; ++sl)       // reuse rmin regs as per-slot thresholds
    rmin[sl] = thrF[(sl >> 2) * 16 + quad * 4 + (sl & 3)];

  // ---- Sweep B: bitwise-identical recompute, exact-threshold append ----
  {
    const ushort* bp = bp0;
    const float* ep = ep0;
    short8 bb[4];
    #pragma unroll
    for (int ks = 0; ks < 4; ++ks) bb[ks] = *(const short8*)(bp + ks * 32);
    float e2v = *ep;
    for (int it = 0; it < 32; ++it) {
      const int adv = (it < 31) ? 8192 : 0;
      const int eadv = (it < 31) ? 64 : 0;
      short8 nb[4];
      #pragma unroll
      for (int ks = 0; ks < 4; ++ks) nb[ks] = *(const short8*)(bp + adv + ks * 32);
      const float ne2 = ep[eadv];
      float4v acc[8];
      #pragma unroll
      for (int rt = 0; rt < 8; ++rt) acc[rt] = vzero;
      #pragma unroll
      for (int ks = 0; ks < 4; ++ks)
        #pragma unroll
        for (int rt = 0; rt < 8; ++rt)
          acc[rt] = __builtin_amdgcn_mfma_f32_16x16x32_bf16(afr[rt][ks], bb[ks], acc[rt], 0, 0, 0);
      const int cbase = it * 64 + wv * 16 + col;
      #pragma unroll
      for (int rt = 0; rt < 8; ++rt)
        #pragma unroll
        for (int r = 0; r < 4; ++r) {
          const float s = fmaf(-2.0f, acc[rt][r], e2v);
          if (s < rmin[rt * 4 + r]) {
            const int rw = rt * 16 + quad * 4 + r;
            const int pos = atomicAdd(&cntL[rw], 1);
            if (pos < 16) candL[rw * 16 + pos] = (ushort)cbase;
          }
        }
      #pragma unroll
      for (int ks = 0; ks < 4; ++ks) bb[ks] = nb[ks];
      e2v = ne2;
      bp += 8192;
      ep += 64;
    }
  }
  __syncthreads();
  if (tid < 128) {
    const int n = n0 + tid;
    candcnt[n] = cntL[tid];
    uint4* dst = (uint4*)(cand_g + (size_t)n * 16);
    const uint4* src = (const uint4*)(candL + tid * 16);
    dst[0] = src[0];
    dst[1] = src[1];
  }
}

// Phase 2: exact np-replica rescore (R2-verified formula) + f64 loss partials.
__global__ __launch_bounds__(256)
void rescore_kernel(const float* __restrict__ z, const float* __restrict__ cb,
                    const float* __restrict__ e2f, const float* __restrict__ Arow,
                    const ushort* __restrict__ cand_g, const int* __restrict__ candcnt,
                    int* __restrict__ idxbuf, int* __restrict__ counts,
                    float* __restrict__ out_idx, double* __restrict__ part) {
  const int tid = threadIdx.x;
  const int n = blockIdx.x * 256 + tid;           // 256 blocks
  const int c = candcnt[n];
  double sq = 0.0;
  if (c >= 1 && c <= 16) {                        // fallback handles the rest
    const int b = n >> 10, t = n & 1023;
    const float* zb = z + (size_t)b * DT + t;
    const float A = Arow[n];
    float best = 1e30f;
    int bk = Kk;
    for (int j = 0; j < c; ++j) {
      const int k = cand_g[(size_t)n * 16 + j];
      const float* e = cb + (size_t)k * Dd;
      double acc = 0.0;
      #pragma unroll 8
      for (int d = 0; d < 128; d += 4) {
        const float4 ev = *(const float4*)(e + d);
        acc += (double)zb[(d + 0) * Tt] * (double)ev.x;
        acc += (double)zb[(d + 1) * Tt] * (double)ev.y;
        acc += (double)zb[(d + 2) * Tt] * (double)ev.z;
        acc += (double)zb[(d + 3) * Tt] * (double)ev.w;
      }
      const float m32 = (float)acc;
      const float X = __fsub_rn(A, __fmul_rn(2.0f, m32));
      const float Dq = __fadd_rn(X, e2f[k]);
      if (Dq < best || (Dq == best && k < bk)) { best = Dq; bk = k; }
    }
    idxbuf[n] = bk;
    out_idx[n] = (float)bk;
    atomicAdd(&counts[bk], 1);
    const float* ew = cb + (size_t)bk * Dd;       // winner loss pass (caches hot)
    #pragma unroll 8
    for (int d = 0; d < 128; ++d) {
      const double dif = (double)zb[d * Tt] - (double)ew[d];
      sq += dif * dif;
    }
  }
  #pragma unroll
  for (int o = 32; o > 0; o >>= 1) sq += __shfl_down(sq, o, 64);
  __shared__ double w4[4];
  if ((tid & 63) == 0) w4[tid >> 6] = sq;
  __syncthreads();
  if (tid == 0) part[blockIdx.x] = w4[0] + w4[1] + w4[2] + w4[3];
}

// Fallback: full exact scan for rows with empty/overflowed lists (expected: none).
__global__ __launch_bounds__(256)
void fallback_kernel(const float* __restrict__ z, const float* __restrict__ cb,
                     const float* __restrict__ e2f, const float* __restrict__ Arow,
                     const int* __restrict__ candcnt, int* __restrict__ idxbuf,
                     int* __restrict__ counts, float* __restrict__ out_idx,
                     double* __restrict__ part) {
  __shared__ int flags[256];
  __shared__ int nf;
  __shared__ float xrow[128];
  __shared__ float rs[256];
  __shared__ int rk[256];
  const int tid = threadIdx.x;
  const int nb = blockIdx.x * 256;                // 256 blocks
  if (tid == 0) { nf = 0; part[256 + blockIdx.x] = 0.0; }
  __syncthreads();
  const int c = candcnt[nb + tid];
  const int bad = (c < 1 || c > 16) ? 1 : 0;
  flags[tid] = bad;
  if (bad) atomicAdd(&nf, 1);
  __syncthreads();
  if (nf == 0) return;                            // fast path
  double bsum = 0.0;
  for (int rr = 0; rr < 256; ++rr) {
    if (!flags[rr]) continue;                     // block-uniform
    const int n = nb + rr;
    const int b = n >> 10, t = n & 1023;
    if (tid < 128) xrow[tid] = z[(size_t)b * DT + (size_t)tid * Tt + t];
    __syncthreads();
    const float A = Arow[n];
    float best = 1e30f;
    int bk = Kk;
    for (int kk = tid * 8; kk < tid * 8 + 8; ++kk) {
      const float* e = cb + (size_t)kk * Dd;
      double acc = 0.0;
      for (int d = 0; d < 128; d += 4) {
        const float4 ev = *(const float4*)(e + d);
        acc += (double)xrow[d + 0] * (double)ev.x;
        acc += (double)xrow[d + 1] * (double)ev.y;
        acc += (double)xrow[d + 2] * (double)ev.z;
        acc += (double)xrow[d + 3] * (double)ev.w;
      }
      const float m32 = (float)acc;
      const float Dq = __fadd_rn(__fsub_rn(A, __fmul_rn(2.0f, m32)), e2f[kk]);
      if (Dq < best || (Dq == best && kk < bk)) { best = Dq; bk = kk; }
    }
    rs[tid] = best;
    rk[tid] = bk;
    __syncthreads();
    for (int o = 128; o > 0; o >>= 1) {
      if (tid < o) {
        if (rs[tid + o] < rs[tid] || (rs[tid + o] == rs[tid] && rk[tid + o] < rk[tid])) {
          rs[tid] = rs[tid + o];
          rk[tid] = rk[tid + o];
        }
      }
      __syncthreads();
    }
    if (tid == 0) {
      const int w = rk[0];
      idxbuf[n] = w;
      out_idx[n] = (float)w;
      atomicAdd(&counts[w], 1);
      const float* ew = cb + (size_t)w * Dd;
      for (int d = 0; d < 128; ++d) {
        const double dif = (double)xrow[d] - (double)ew[d];
        bsum += dif * dif;
      }
    }
    __syncthreads();
  }
  if (tid == 0) part[256 + blockIdx.x] = bsum;
}

// Gather z_q into (B,D,T) layout (z_q_st == z_q in value; no z read needed).
__global__ __launch_bounds__(256)
void gather_kernel(const float* __restrict__ cb, const int* __restrict__ idxbuf,
                   float* __restrict__ out0) {
  const int tid = threadIdx.x;
  const size_t o0 = ((size_t)blockIdx.x * 256 + tid) * 8;  // 4096 blocks
  const int b = (int)(o0 >> 17);
  const int dt = (int)(o0 & (size_t)(DT - 1));
  const int d = dt >> 10;
  const int t = dt & 1023;
  const int n = (b << 10) + t;
  float q[8];
  #pragma unroll
  for (int j = 0; j < 8; ++j) q[j] = cb[(size_t)idxbuf[n + j] * Dd + d];
  *(float4*)(out0 + o0)     = make_float4(q[0], q[1], q[2], q[3]);
  *(float4*)(out0 + o0 + 4) = make_float4(q[4], q[5], q[6], q[7]);
}

__global__ __launch_bounds__(256)
void finalize_kernel(const int* __restrict__ counts, const double* __restrict__ part,
                     float* __restrict__ out) {
  const int tid = threadIdx.x;
  __shared__ double red[256];
  double s = 0.0;
  for (int i = tid; i < 512; i += 256) s += part[i];
  red[tid] = s;
  __syncthreads();
  for (int o = 128; o > 0; o >>= 1) {
    if (tid < o) red[tid] += red[tid + o];
    __syncthreads();
  }
  const double loss = red[0];
  __syncthreads();
  double e = 0.0;
  for (int k = tid; k < 2048; k += 256) {
    const double p = (double)counts[k] / 65536.0;
    e += p * log(p + 1e-10);
  }
  red[tid] = e;
  __syncthreads();
  for (int o = 128; o > 0; o >>= 1) {
    if (tid < o) red[tid] += red[tid + o];
    __syncthreads();
  }
  if (tid == 0) {
    out[8388608] = (float)(0.25 * loss / 8388608.0);
    out[8388609] = (float)exp(-red[0]);
  }
}

extern "C" void kernel_launch(void* const* d_in, const int* in_sizes, int n_in,
                              void* d_out, int out_size, void* d_ws, size_t ws_size,
                              hipStream_t stream) {
  const float* z = (const float*)d_in[0];      // (B, D, T) fp32
  const float* cb = (const float*)d_in[1];     // (K, D) fp32
  float* out = (float*)d_out;                  // [z_q (8388608) | loss | perp | idx (65536)]
  char* ws = (char*)d_ws;
  ushort* cbh    = (ushort*)ws;
  float* e2f     = (float*)(ws + 524288);
  float* Arow    = (float*)(ws + 532480);
  int* idxbuf    = (int*)(ws + 794624);
  int* counts    = (int*)(ws + 1056768);
  double* part   = (double*)(ws + 1064960);
  ushort* cand_g = (ushort*)(ws + 1069056);
  int* candcnt   = (int*)(ws + 3166208);

  hipLaunchKernelGGL(setup_kernel,    dim3(1288), dim3(256), 0, stream, cb, z, cbh, e2f, Arow, counts);
  hipLaunchKernelGGL(score_kernel,    dim3(512),  dim3(256), 0, stream, z, cbh, e2f, Arow,
                     cand_g, candcnt);
  hipLaunchKernelGGL(rescore_kernel,  dim3(256),  dim3(256), 0, stream, z, cb, e2f, Arow,
                     cand_g, candcnt, idxbuf, counts, out + 8388610, part);
  hipLaunchKernelGGL(fallback_kernel, dim3(256),  dim3(256), 0, stream, z, cb, e2f, Arow,
                     candcnt, idxbuf, counts, out + 8388610, part);
  hipLaunchKernelGGL(gather_kernel,   dim3(4096), dim3(256), 0, stream, cb, idxbuf, out);
  hipLaunchKernelGGL(finalize_kernel, dim3(1),    dim3(256), 0, stream, counts, part, out);
}

// Round 4
// 266.380 us; speedup vs baseline: 3.5269x; 1.0642x over previous
//
#include <hip/hip_runtime.h>
#include <math.h>

#define Dd 128
#define Tt 1024
#define Kk 2048
#define Nn 65536
#define DT 131072  // Dd*Tt

typedef __attribute__((ext_vector_type(8))) short short8;
typedef __attribute__((ext_vector_type(4))) float float4v;

// ws layout (bytes):
//   cbh     @ 0        : ushort[262144] = 524288   (bf16 hi plane of codebook, SOA-fragment layout)
//   e2f     @ 524288   : float[2048]    = 8192     (np-replica fp32 ||e||^2)
//   Arow    @ 532480   : float[65536]   = 262144   (np-replica fp32 ||x||^2)
//   idxbuf  @ 794624   : int[65536]     = 262144
//   counts  @ 1056768  : int[2048]      = 8192
//   part    @ 1064960  : double[512]    = 4096
//   cand_g  @ 1069056  : ushort[65536*16] = 2097152
//   candcnt @ 3166208  : int[65536]     = 262144
// total 3428352 B (~3.43 MB)
//
// cbh SOA layout: for code k, 16B granule g (g of the 256B row):
//   chunk=k>>6, wv=(k>>4)&3, col=k&15, ks=g>>2, quad=g&3
//   byte dest = chunk*16384 + wv*4096 + ks*1024 + quad*256 + col*16
// => score_kernel's per-(wave,iter,ks) B-fragment load is lane*16B contiguous
//    (1 KB fully-coalesced per instruction instead of 16 scattered segments).

// Fused setup: SOA bf16-hi split of codebook (blocks 0..127), np-replica fp32
// ||e||^2 + counts-zero + part[0..255]-zero (blocks 128..135), np-replica
// fp32 ||x||^2 (blocks 136..391). numpy pairwise order for n=128: 8
// accumulators, sequential i, combine ((r0+r1)+(r2+r3))+((r4+r5)+(r6+r7));
// __f*_rn blocks FMA contraction so each square rounds like numpy.
__global__ __launch_bounds__(256)
void setup_kernel(const float* __restrict__ cb, const float* __restrict__ z,
                  ushort* __restrict__ cbh, float* __restrict__ e2f,
                  float* __restrict__ Arow, int* __restrict__ counts,
                  double* __restrict__ part) {
  const int bid = blockIdx.x, tid = threadIdx.x;
  if (bid < 128) {
    const int gi = bid * 256 + tid;               // 32768 granules (16B each)
    const int k = gi >> 4, g = gi & 15;
    const float* p = cb + (size_t)k * Dd + g * 8; // 32B coalesced read
    short8 w;
    #pragma unroll
    for (int j = 0; j < 8; ++j) {
      const unsigned u = __float_as_uint(p[j]);
      const unsigned hb = (u + 0x7FFFu + ((u >> 16) & 1u)) & 0xFFFF0000u;  // RNE bf16
      w[j] = (short)(hb >> 16);
    }
    const int chunk = k >> 6, wvv = (k >> 4) & 3, colc = k & 15;
    *(short8*)((char*)cbh + chunk * 16384 + wvv * 4096 + (g >> 2) * 1024 +
               (g & 3) * 256 + colc * 16) = w;
  } else if (bid < 136) {
    const int k = (bid - 128) * 256 + tid;        // 2048 codes
    counts[k] = 0;
    if (tid < 32) part[(bid - 128) * 32 + tid] = 0.0;  // zero rescore-era slots
    const float* p = cb + (size_t)k * Dd;
    float r[8];
    #pragma unroll
    for (int j = 0; j < 8; ++j) r[j] = __fmul_rn(p[j], p[j]);
    for (int i = 1; i < 16; ++i) {
      #pragma unroll
      for (int j = 0; j < 8; ++j) {
        const float v = p[8 * i + j];
        r[j] = __fadd_rn(r[j], __fmul_rn(v, v));
      }
    }
    e2f[k] = __fadd_rn(__fadd_rn(__fadd_rn(r[0], r[1]), __fadd_rn(r[2], r[3])),
                       __fadd_rn(__fadd_rn(r[4], r[5]), __fadd_rn(r[6], r[7])));
  } else {
    const int g = (bid - 136) * 256 + tid;        // 65536 rows
    const int b = g >> 10, t = g & 1023;
    const float* p = z + (size_t)b * DT + t;      // x_d = p[d*Tt]
    float r[8];
    #pragma unroll
    for (int j = 0; j < 8; ++j) {
      const float v = p[j * Tt];
      r[j] = __fmul_rn(v, v);
    }
    for (int i = 1; i < 16; ++i) {
      #pragma unroll
      for (int j = 0; j < 8; ++j) {
        const float v = p[(8 * i + j) * Tt];
        r[j] = __fadd_rn(r[j], __fmul_rn(v, v));
      }
    }
    Arow[g] = __fadd_rn(__fadd_rn(__fadd_rn(r[0], r[1]), __fadd_rn(r[2], r[3])),
                        __fadd_rn(__fadd_rn(r[4], r[5]), __fadd_rn(r[6], r[7])));
  }
}

// Phase 1: two-sweep hi-plane bf16 MFMA scoring, barrier-free main loops,
// SOA-coalesced B loads. 128 rows/block (512 blocks), 4 waves; each wave owns
// all 128 rows and a 16-col slice of each 64-code chunk. A (z rows, bf16-hi)
// lives in VGPRs for the whole kernel; B is loaded global->VGPR from the SOA
// cbh: per iter per wave = 4x dwordx4 loads at lane*16B (fully coalesced 1KB)
// + 1 e2 dword. 1-deep register prefetch; no LDS in the loops.
// Sweep A: per-lane running min -> shfl over 16 cols -> LDS reduce over 4
// waves -> exact row-global min m. Sweep B: bitwise-identical recompute,
// append codes with s < m + marg_row (marg_row = 8.7e-5*sqrt(Arow)+1e-4,
// same deterministic bound as the verified baseline). Cap 16; candcnt>16 ->
// exact fallback (expected: none).
__global__ __launch_bounds__(256, 2)
void score_kernel(const float* __restrict__ z, const ushort* __restrict__ cbh,
                  const float* __restrict__ e2f, const float* __restrict__ Arow,
                  ushort* __restrict__ cand_g, int* __restrict__ candcnt) {
  __shared__ __attribute__((aligned(16))) ushort zh[16384]; // 32KB z hi plane
  __shared__ float margL[128];
  __shared__ float sredA[512];       // [row][wv]
  __shared__ float thrF[128];
  __shared__ int cntL[128];
  __shared__ ushort candL[128 * 16]; // 4KB

  const int tid = threadIdx.x;
  const int n0 = blockIdx.x * 128;               // 512 blocks
  const int b = n0 >> 10, t0 = n0 & 1023;
  const float* zb = z + (size_t)b * DT + t0;
  const int lane = tid & 63, wv = tid >> 6;
  const int col = lane & 15, quad = lane >> 4;

  // ---- prologue: stage z hi plane (128 rows x 128 d, 16B-granule swizzled) ----
  {
    const int i = tid & 127;          // row in block
    const int half = tid >> 7;        // 0/1
    #pragma unroll
    for (int g8 = 0; g8 < 8; ++g8) {
      const int gran = half * 8 + g8;
      short8 w;
      #pragma unroll
      for (int j = 0; j < 8; ++j) {
        const int d = gran * 8 + j;
        const float v = zb[d * Tt + i];            // coalesced over i
        const unsigned u = __float_as_uint(v);
        const unsigned hb = (u + 0x7FFFu + ((u >> 16) & 1u)) & 0xFFFF0000u;
        w[j] = (short)(hb >> 16);
      }
      *(short8*)&zh[i * 128 + ((gran ^ (i & 15)) << 3)] = w;
    }
  }
  if (tid < 128) {
    margL[tid] = 8.7e-5f * sqrtf(Arow[n0 + tid]) + 1.0e-4f;
    cntL[tid] = 0;
  }
  __syncthreads();

  // ---- A fragments into registers (all 128 rows per wave, K=128) ----
  short8 afr[8][4];
  #pragma unroll
  for (int rt = 0; rt < 8; ++rt)
    #pragma unroll
    for (int ks = 0; ks < 4; ++ks) {
      const int rw = rt * 16 + col;               // rw&15 == col
      afr[rt][ks] = *(const short8*)&zh[rw * 128 + (((ks * 4 + quad) ^ col) << 3)];
    }

  // per-lane B base in the SOA layout: wave slice + lane*16B; ks -> +1024B imm
  const ushort* const bp0 = cbh + wv * 2048 + lane * 8;   // ushort units
  const float* const ep0 = e2f + wv * 16 + col;

  const float4v vzero = {0.f, 0.f, 0.f, 0.f};
  float rmin[32];
  #pragma unroll
  for (int sl = 0; sl < 32; ++sl) rmin[sl] = 1e30f;

  // ---- Sweep A: exact row-global min over bf16-hi scores (barrier-free) ----
  {
    const ushort* bp = bp0;
    const float* ep = ep0;
    short8 bb[4];
    #pragma unroll
    for (int ks = 0; ks < 4; ++ks) bb[ks] = *(const short8*)(bp + ks * 512);
    float e2v = *ep;
    for (int it = 0; it < 32; ++it) {
      const int adv = (it < 31) ? 8192 : 0;       // prefetch next chunk (clamped)
      const int eadv = (it < 31) ? 64 : 0;
      short8 nb[4];
      #pragma unroll
      for (int ks = 0; ks < 4; ++ks) nb[ks] = *(const short8*)(bp + adv + ks * 512);
      const float ne2 = ep[eadv];
      float4v acc[8];
      #pragma unroll
      for (int rt = 0; rt < 8; ++rt) acc[rt] = vzero;
      #pragma unroll
      for (int ks = 0; ks < 4; ++ks)
        #pragma unroll
        for (int rt = 0; rt < 8; ++rt)
          acc[rt] = __builtin_amdgcn_mfma_f32_16x16x32_bf16(afr[rt][ks], bb[ks], acc[rt], 0, 0, 0);
      #pragma unroll
      for (int rt = 0; rt < 8; ++rt)
        #pragma unroll
        for (int r = 0; r < 4; ++r) {
          const float s = fmaf(-2.0f, acc[rt][r], e2v);
          rmin[rt * 4 + r] = fminf(rmin[rt * 4 + r], s);
        }
      #pragma unroll
      for (int ks = 0; ks < 4; ++ks) bb[ks] = nb[ks];
      e2v = ne2;
      bp += 8192;
      ep += 64;
    }
  }

  // ---- exact row-global min reduce: 16 cols (shfl) x 4 waves (LDS) ----
  #pragma unroll
  for (int sl = 0; sl < 32; ++sl) {
    float v = rmin[sl];
    v = fminf(v, __shfl_xor(v, 1, 64));
    v = fminf(v, __shfl_xor(v, 2, 64));
    v = fminf(v, __shfl_xor(v, 4, 64));
    v = fminf(v, __shfl_xor(v, 8, 64));
    rmin[sl] = v;
  }
  if (col == 0) {
    #pragma unroll
    for (int sl = 0; sl < 32; ++sl) {
      const int rw = (sl >> 2) * 16 + quad * 4 + (sl & 3);
      sredA[rw * 4 + wv] = rmin[sl];
    }
  }
  __syncthreads();
  if (tid < 128) {
    const float m = fminf(fminf(sredA[tid * 4], sredA[tid * 4 + 1]),
                          fminf(sredA[tid * 4 + 2], sredA[tid * 4 + 3]));
    thrF[tid] = m + margL[tid];
  }
  __syncthreads();
  #pragma unroll
  for (int sl = 0; sl < 32; ++sl)       // reuse rmin regs as per-slot thresholds
    rmin[sl] = thrF[(sl >> 2) * 16 + quad * 4 + (sl & 3)];

  // ---- Sweep B: bitwise-identical recompute, exact-threshold append ----
  {
    const ushort* bp = bp0;
    const float* ep = ep0;
    short8 bb[4];
    #pragma unroll
    for (int ks = 0; ks < 4; ++ks) bb[ks] = *(const short8*)(bp + ks * 512);
    float e2v = *ep;
    for (int it = 0; it < 32; ++it) {
      const int adv = (it < 31) ? 8192 : 0;
      const int eadv = (it < 31) ? 64 : 0;
      short8 nb[4];
      #pragma unroll
      for (int ks = 0; ks < 4; ++ks) nb[ks] = *(const short8*)(bp + adv + ks * 512);
      const float ne2 = ep[eadv];
      float4v acc[8];
      #pragma unroll
      for (int rt = 0; rt < 8; ++rt) acc[rt] = vzero;
      #pragma unroll
      for (int ks = 0; ks < 4; ++ks)
        #pragma unroll
        for (int rt = 0; rt < 8; ++rt)
          acc[rt] = __builtin_amdgcn_mfma_f32_16x16x32_bf16(afr[rt][ks], bb[ks], acc[rt], 0, 0, 0);
      const int cbase = it * 64 + wv * 16 + col;
      #pragma unroll
      for (int rt = 0; rt < 8; ++rt)
        #pragma unroll
        for (int r = 0; r < 4; ++r) {
          const float s = fmaf(-2.0f, acc[rt][r], e2v);
          if (s < rmin[rt * 4 + r]) {
            const int rw = rt * 16 + quad * 4 + r;
            const int pos = atomicAdd(&cntL[rw], 1);
            if (pos < 16) candL[rw * 16 + pos] = (ushort)cbase;
          }
        }
      #pragma unroll
      for (int ks = 0; ks < 4; ++ks) bb[ks] = nb[ks];
      e2v = ne2;
      bp += 8192;
      ep += 64;
    }
  }
  __syncthreads();
  if (tid < 128) {
    const int n = n0 + tid;
    candcnt[n] = cntL[tid];
    uint4* dst = (uint4*)(cand_g + (size_t)n * 16);
    const uint4* src = (const uint4*)(candL + tid * 16);
    dst[0] = src[0];
    dst[1] = src[1];
  }
}

// Phase 2: exact np-replica rescore (R2-verified formula). Loss moved to
// gather_kernel (coalesced z there); this kernel only picks the winner.
__global__ __launch_bounds__(256)
void rescore_kernel(const float* __restrict__ z, const float* __restrict__ cb,
                    const float* __restrict__ e2f, const float* __restrict__ Arow,
                    const ushort* __restrict__ cand_g, const int* __restrict__ candcnt,
                    int* __restrict__ idxbuf, int* __restrict__ counts,
                    float* __restrict__ out_idx) {
  const int tid = threadIdx.x;
  const int n = blockIdx.x * 256 + tid;           // 256 blocks
  const int c = candcnt[n];
  if (c >= 1 && c <= 16) {                        // fallback handles the rest
    const int b = n >> 10, t = n & 1023;
    const float* zb = z + (size_t)b * DT + t;
    const float A = Arow[n];
    float best = 1e30f;
    int bk = Kk;
    for (int j = 0; j < c; ++j) {
      const int k = cand_g[(size_t)n * 16 + j];
      const float* e = cb + (size_t)k * Dd;
      double acc = 0.0;
      #pragma unroll 8
      for (int d = 0; d < 128; d += 4) {
        const float4 ev = *(const float4*)(e + d);
        acc += (double)zb[(d + 0) * Tt] * (double)ev.x;
        acc += (double)zb[(d + 1) * Tt] * (double)ev.y;
        acc += (double)zb[(d + 2) * Tt] * (double)ev.z;
        acc += (double)zb[(d + 3) * Tt] * (double)ev.w;
      }
      const float m32 = (float)acc;
      const float X = __fsub_rn(A, __fmul_rn(2.0f, m32));
      const float Dq = __fadd_rn(X, e2f[k]);
      if (Dq < best || (Dq == best && k < bk)) { best = Dq; bk = k; }
    }
    idxbuf[n] = bk;
    out_idx[n] = (float)bk;
    atomicAdd(&counts[bk], 1);
  }
}

// Fallback: full exact scan for rows with empty/overflowed lists (expected:
// none). Zeroes the part[256..511] slots gather accumulates into.
__global__ __launch_bounds__(256)
void fallback_kernel(const float* __restrict__ z, const float* __restrict__ cb,
                     const float* __restrict__ e2f, const float* __restrict__ Arow,
                     const int* __restrict__ candcnt, int* __restrict__ idxbuf,
                     int* __restrict__ counts, float* __restrict__ out_idx,
                     double* __restrict__ part) {
  __shared__ int flags[256];
  __shared__ int nf;
  __shared__ float xrow[128];
  __shared__ float rs[256];
  __shared__ int rk[256];
  const int tid = threadIdx.x;
  const int nb = blockIdx.x * 256;                // 256 blocks
  if (tid == 0) { nf = 0; part[256 + blockIdx.x] = 0.0; }
  __syncthreads();
  const int c = candcnt[nb + tid];
  const int bad = (c < 1 || c > 16) ? 1 : 0;
  flags[tid] = bad;
  if (bad) atomicAdd(&nf, 1);
  __syncthreads();
  if (nf == 0) return;                            // fast path
  for (int rr = 0; rr < 256; ++rr) {
    if (!flags[rr]) continue;                     // block-uniform
    const int n = nb + rr;
    const int b = n >> 10, t = n & 1023;
    if (tid < 128) xrow[tid] = z[(size_t)b * DT + (size_t)tid * Tt + t];
    __syncthreads();
    const float A = Arow[n];
    float best = 1e30f;
    int bk = Kk;
    for (int kk = tid * 8; kk < tid * 8 + 8; ++kk) {
      const float* e = cb + (size_t)kk * Dd;
      double acc = 0.0;
      for (int d = 0; d < 128; d += 4) {
        const float4 ev = *(const float4*)(e + d);
        acc += (double)xrow[d + 0] * (double)ev.x;
        acc += (double)xrow[d + 1] * (double)ev.y;
        acc += (double)xrow[d + 2] * (double)ev.z;
        acc += (double)xrow[d + 3] * (double)ev.w;
      }
      const float m32 = (float)acc;
      const float Dq = __fadd_rn(__fsub_rn(A, __fmul_rn(2.0f, m32)), e2f[kk]);
      if (Dq < best || (Dq == best && kk < bk)) { best = Dq; bk = kk; }
    }
    rs[tid] = best;
    rk[tid] = bk;
    __syncthreads();
    for (int o = 128; o > 0; o >>= 1) {
      if (tid < o) {
        if (rs[tid + o] < rs[tid] || (rs[tid + o] == rs[tid] && rk[tid + o] < rk[tid])) {
          rs[tid] = rs[tid + o];
          rk[tid] = rk[tid + o];
        }
      }
      __syncthreads();
    }
    if (tid == 0) {
      const int w = rk[0];
      idxbuf[n] = w;
      out_idx[n] = (float)w;
      atomicAdd(&counts[w], 1);
    }
    __syncthreads();
  }
}

// Gather z_q into (B,D,T) layout + commitment-loss partials (z read is
// COALESCED here, unlike the strided per-row pass this replaces in rescore).
__global__ __launch_bounds__(256)
void gather_kernel(const float* __restrict__ cb, const int* __restrict__ idxbuf,
                   const float* __restrict__ z, float* __restrict__ out0,
                   double* __restrict__ part) {
  const int tid = threadIdx.x;
  const size_t o0 = ((size_t)blockIdx.x * 256 + tid) * 8;  // 4096 blocks
  const int b = (int)(o0 >> 17);
  const int dt = (int)(o0 & (size_t)(DT - 1));
  const int d = dt >> 10;
  const int t = dt & 1023;
  const int n = (b << 10) + t;
  float q[8];
  #pragma unroll
  for (int j = 0; j < 8; ++j) q[j] = cb[(size_t)idxbuf[n + j] * Dd + d];
  const float4 z0 = *(const float4*)(z + o0);
  const float4 z1 = *(const float4*)(z + o0 + 4);
  *(float4*)(out0 + o0)     = make_float4(q[0], q[1], q[2], q[3]);
  *(float4*)(out0 + o0 + 4) = make_float4(q[4], q[5], q[6], q[7]);
  double sq = 0.0;
  {
    const float zz[8] = {z0.x, z0.y, z0.z, z0.w, z1.x, z1.y, z1.z, z1.w};
    #pragma unroll
    for (int j = 0; j < 8; ++j) {
      const double dif = (double)zz[j] - (double)q[j];
      sq += dif * dif;
    }
  }
  #pragma unroll
  for (int o = 32; o > 0; o >>= 1) sq += __shfl_down(sq, o, 64);
  __shared__ double w4[4];
  if ((tid & 63) == 0) w4[tid >> 6] = sq;
  __syncthreads();
  if (tid == 0) atomicAdd(&part[256 + (blockIdx.x & 255)], w4[0] + w4[1] + w4[2] + w4[3]);
}

__global__ __launch_bounds__(256)
void finalize_kernel(const int* __restrict__ counts, const double* __restrict__ part,
                     float* __restrict__ out) {
  const int tid = threadIdx.x;
  __shared__ double red[256];
  double s = 0.0;
  for (int i = tid; i < 512; i += 256) s += part[i];
  red[tid] = s;
  __syncthreads();
  for (int o = 128; o > 0; o >>= 1) {
    if (tid < o) red[tid] += red[tid + o];
    __syncthreads();
  }
  const double loss = red[0];
  __syncthreads();
  double e = 0.0;
  for (int k = tid; k < 2048; k += 256) {
    const double p = (double)counts[k] / 65536.0;
    e += p * log(p + 1e-10);
  }
  red[tid] = e;
  __syncthreads();
  for (int o = 128; o > 0; o >>= 1) {
    if (tid < o) red[tid] += red[tid + o];
    __syncthreads();
  }
  if (tid == 0) {
    out[8388608] = (float)(0.25 * loss / 8388608.0);
    out[8388609] = (float)exp(-red[0]);
  }
}

extern "C" void kernel_launch(void* const* d_in, const int* in_sizes, int n_in,
                              void* d_out, int out_size, void* d_ws, size_t ws_size,
                              hipStream_t stream) {
  const float* z = (const float*)d_in[0];      // (B, D, T) fp32
  const float* cb = (const float*)d_in[1];     // (K, D) fp32
  float* out = (float*)d_out;                  // [z_q (8388608) | loss | perp | idx (65536)]
  char* ws = (char*)d_ws;
  ushort* cbh    = (ushort*)ws;
  float* e2f     = (float*)(ws + 524288);
  float* Arow    = (float*)(ws + 532480);
  int* idxbuf    = (int*)(ws + 794624);
  int* counts    = (int*)(ws + 1056768);
  double* part   = (double*)(ws + 1064960);
  ushort* cand_g = (ushort*)(ws + 1069056);
  int* candcnt   = (int*)(ws + 3166208);

  hipLaunchKernelGGL(setup_kernel,    dim3(392),  dim3(256), 0, stream, cb, z, cbh, e2f, Arow,
                     counts, part);
  hipLaunchKernelGGL(score_kernel,    dim3(512),  dim3(256), 0, stream, z, cbh, e2f, Arow,
                     cand_g, candcnt);
  hipLaunchKernelGGL(rescore_kernel,  dim3(256),  dim3(256), 0, stream, z, cb, e2f, Arow,
                     cand_g, candcnt, idxbuf, counts, out + 8388610);
  hipLaunchKernelGGL(fallback_kernel, dim3(256),  dim3(256), 0, stream, z, cb, e2f, Arow,
                     candcnt, idxbuf, counts, out + 8388610, part);
  hipLaunchKernelGGL(gather_kernel,   dim3(4096), dim3(256), 0, stream, cb, idxbuf, z, out, part);
  hipLaunchKernelGGL(finalize_kernel, dim3(1),    dim3(256), 0, stream, counts, part, out);
}